// Round 1
// baseline (1216.959 us; speedup 1.0000x reference)
//
#include <hip/hip_runtime.h>

#define NN 4096

// Scratch in the device image -- fully rewritten before every read on every
// call (stateless across calls).
__device__ float g_outf[NN*8];
__device__ float g_agg0[NN*8];
__device__ float g_agg1[NN*8];
__device__ unsigned g_bar;    // zero at load; reset to zero by every barrier
__device__ unsigned g_sense;  // monotonically increasing generation counter

__device__ __forceinline__ float lrelu(float x){ return x > 0.0f ? x : 0.01f * x; }

// Full 3-layer MLP (8->16->8->8), leaky_relu(0.01) after every layer.
__device__ void mlp3(const float* in,
                     const float* W1, const float* b1,
                     const float* W2, const float* b2,
                     const float* W3, const float* b3, float* out)
{
  float h1[16];
  #pragma unroll
  for (int m=0;m<16;m++){
    float s = b1[m];
    #pragma unroll
    for (int k=0;k<8;k++) s += in[k]*W1[k*16+m];
    h1[m] = lrelu(s);
  }
  float h2[8];
  #pragma unroll
  for (int m=0;m<8;m++){
    float s = b2[m];
    #pragma unroll
    for (int k=0;k<16;k++) s += h1[k]*W2[k*8+m];
    h2[m] = lrelu(s);
  }
  #pragma unroll
  for (int c=0;c<8;c++){
    float s = b3[c];
    #pragma unroll
    for (int k=0;k<8;k++) s += h2[k]*W3[k*8+c];
    out[c] = lrelu(s);
  }
}

// Device-wide sense-reversing barrier. grid == 256 blocks == #CUs, 0 LDS,
// <=256 VGPR -> all blocks always resident (capacity >= 2 blocks/CU).
// __threadfence() on gfx950 emits the agent-scope wbL2/invL1L2 needed for
// cross-XCD visibility of aggout between depths.
__device__ __forceinline__ void grid_sync()
{
  __threadfence();
  __syncthreads();
  if (threadIdx.x == 0){
    unsigned gen = __hip_atomic_load(&g_sense, __ATOMIC_ACQUIRE, __HIP_MEMORY_SCOPE_AGENT);
    unsigned n   = __hip_atomic_fetch_add(&g_bar, 1u, __ATOMIC_ACQ_REL, __HIP_MEMORY_SCOPE_AGENT);
    if (n == gridDim.x - 1u){
      __hip_atomic_store(&g_bar, 0u, __ATOMIC_RELAXED, __HIP_MEMORY_SCOPE_AGENT);
      __hip_atomic_store(&g_sense, gen + 1u, __ATOMIC_RELEASE, __HIP_MEMORY_SCOPE_AGENT);
    } else {
      while (__hip_atomic_load(&g_sense, __ATOMIC_ACQUIRE, __HIP_MEMORY_SCOPE_AGENT) == gen)
        __builtin_amdgcn_s_sleep(2);
    }
  }
  __syncthreads();
  __threadfence();
}

__global__ __launch_bounds__(256,1) void fused_graph(
    const float* __restrict__ x, const float* __restrict__ rem,
    float* __restrict__ finout,
    const float* __restrict__ pW1,const float* __restrict__ pb1,
    const float* __restrict__ pW2,const float* __restrict__ pb2,
    const float* __restrict__ pW3,const float* __restrict__ pb3,
    const float* __restrict__ aW1,const float* __restrict__ ab1,
    const float* __restrict__ aW2,const float* __restrict__ ab2,
    const float* __restrict__ aW3,const float* __restrict__ ab3)
{
  const int lane = threadIdx.x & 63;
  const int wav  = threadIdx.x >> 6;
  const int i0   = (blockIdx.x*4 + wav) * 4;   // 4 rows per wave

  // Depth-0 per-row pointers (float4 granularity, lane offset folded in).
  const float4* A0p = reinterpret_cast<const float4*>(rem + (size_t)(i0+0)*NN) + lane;
  const float4* A1p = reinterpret_cast<const float4*>(rem + (size_t)(i0+1)*NN) + lane;
  const float4* A2p = reinterpret_cast<const float4*>(rem + (size_t)(i0+2)*NN) + lane;
  const float4* A3p = reinterpret_cast<const float4*>(rem + (size_t)(i0+3)*NN) + lane;

  // Cross-barrier prefetch: depth-0 it=0 A chunk is a pure input,
  // independent of init -- issue before the first grid barrier.
  float4 nA0 = A0p[0], nA1 = A1p[0], nA2 = A2p[0], nA3 = A3p[0];

  // ---- init phase: out0 = MLP_p(x); agg0 = MLP_a(out0). Thread-per-row.
  if (blockIdx.x < 16){
    const int i = blockIdx.x*256 + threadIdx.x;
    float in[8];
    #pragma unroll
    for (int k=0;k<8;k++) in[k] = x[i*8+k];
    float o[8];
    mlp3(in, pW1,pb1,pW2,pb2,pW3,pb3, o);
    #pragma unroll
    for (int c=0;c<8;c++) g_outf[i*8+c] = o[c];
    float a[8];
    mlp3(o, aW1,ab1,aW2,ab2,aW3,ab3, a);
    #pragma unroll
    for (int c=0;c<8;c++) g_agg0[i*8+c] = a[c];
  }
  grid_sync();

  const size_t DSTEP = (size_t)NN*(NN/4);   // float4s per depth slice

  for (int d=0; d<8; ++d){
    const float* aggin  = (d&1) ? g_agg1 : g_agg0;
    float*       aggout = (d&1) ? g_agg0 : g_agg1;
    const float4* gp  = reinterpret_cast<const float4*>(aggin) + (size_t)lane*8;
    const float4* Ad0 = A0p + (size_t)d*DSTEP;
    const float4* Ad1 = A1p + (size_t)d*DSTEP;
    const float4* Ad2 = A2p + (size_t)d*DSTEP;
    const float4* Ad3 = A3p + (size_t)d*DSTEP;

    float acc[4][8];
    #pragma unroll
    for (int r=0;r<4;r++)
      #pragma unroll
      for (int c=0;c<8;c++) acc[r][c] = 0.0f;

    // current A regs come from the prefetch issued last depth (or pre-init)
    float4 cA0=nA0, cA1=nA1, cA2=nA2, cA3=nA3;

    // lane l covers j = it*256 + 4*l .. +3; wave covers 256 j per iteration
    for (int it=0; it<16; ++it){
      // prefetch next iteration's A rows (one iteration ahead)
      float4 fA0, fA1, fA2, fA3;
      if (it < 15){
        fA0 = Ad0[(it+1)*64];
        fA1 = Ad1[(it+1)*64];
        fA2 = Ad2[(it+1)*64];
        fA3 = Ad3[(it+1)*64];
      }
      // current-iteration agg loads (L2/LLC resident, just-in-time)
      float4 G[8];
      #pragma unroll
      for (int t=0;t<8;t++) G[t] = gp[(size_t)it*512 + t];

      const float av[4][4] = {{cA0.x,cA0.y,cA0.z,cA0.w},
                              {cA1.x,cA1.y,cA1.z,cA1.w},
                              {cA2.x,cA2.y,cA2.z,cA2.w},
                              {cA3.x,cA3.y,cA3.z,cA3.w}};
      #pragma unroll
      for (int jj=0;jj<4;jj++){
        const float gl[8] = {G[2*jj].x, G[2*jj].y, G[2*jj].z, G[2*jj].w,
                             G[2*jj+1].x, G[2*jj+1].y, G[2*jj+1].z, G[2*jj+1].w};
        #pragma unroll
        for (int r=0;r<4;r++){
          const float a = av[r][jj];
          #pragma unroll
          for (int c=0;c<8;c++) acc[r][c] += a*gl[c];
        }
      }
      if (it < 15){ cA0=fA0; cA1=fA1; cA2=fA2; cA3=fA3; }
    }

    // Issue next depth's it=0 A loads NOW -- they are barrier-independent and
    // their latency hides under butterfly + epilogue + grid barrier.
    if (d < 7){
      nA0 = Ad0[DSTEP];
      nA1 = Ad1[DSTEP];
      nA2 = Ad2[DSTEP];
      nA3 = Ad3[DSTEP];
    }

    // 64-lane butterfly reduce: afterwards every lane holds all 32 totals
    #pragma unroll
    for (int r=0;r<4;r++)
      #pragma unroll
      for (int c=0;c<8;c++){
        float v = acc[r][c];
        #pragma unroll
        for (int s=1;s<64;s<<=1) v += __shfl_xor(v, s, 64);
        acc[r][c] = v;
      }

    const int r = lane >> 4, m = lane & 15;
    float* po = g_outf + (size_t)i0*8;

    // new out row for this lane's MLP row (r = lane>>4); loads precede the
    // po stores below in wave program order
    float rowv[8];
    #pragma unroll
    for (int k=0;k<8;k++) rowv[k] = po[r*8+k] + acc[r][k];

    // lanes 0..31 write the 32 updated out values
    if (lane < 32){
      float t = 0.0f;
      #pragma unroll
      for (int rr=0;rr<4;rr++)
        #pragma unroll
        for (int cc=0;cc<8;cc++)
          if (rr*8+cc == lane) t = acc[rr][cc];
      float sv = po[lane] + t;
      po[lane] = sv;
      if (d == 7) finout[(size_t)i0*8 + lane] = sv;
    }

    if (d < 7){
      // lane-parallel MLP_a over 4 rows x 16 neurons
      float h1 = ab1[m];
      #pragma unroll
      for (int k=0;k<8;k++) h1 += rowv[k]*aW1[k*16+m];
      h1 = lrelu(h1);
      const int m8 = m & 7;
      float s2 = ab2[m8];
      #pragma unroll
      for (int k=0;k<16;k++) s2 += __shfl(h1, (lane & 48)+k, 64) * aW2[k*8+m8];
      float h2 = lrelu(s2);
      float s3 = ab3[m8];
      #pragma unroll
      for (int k=0;k<8;k++) s3 += __shfl(h2, (lane & 48)+k, 64) * aW3[k*8+m8];
      float av2 = lrelu(s3);
      if (m < 8) aggout[(size_t)(i0+r)*8 + m] = av2;

      grid_sync();
    }
  }
}

extern "C" void kernel_launch(void* const* d_in, const int* in_sizes, int n_in,
                              void* d_out, int out_size, void* d_ws, size_t ws_size,
                              hipStream_t stream)
{
  const float* x   = (const float*)d_in[0];
  const float* rem = (const float*)d_in[1];
  const float* pW1 = (const float*)d_in[2];
  const float* pb1 = (const float*)d_in[3];
  const float* pW2 = (const float*)d_in[4];
  const float* pb2 = (const float*)d_in[5];
  const float* pW3 = (const float*)d_in[6];
  const float* pb3 = (const float*)d_in[7];
  const float* aW1 = (const float*)d_in[8];
  const float* ab1 = (const float*)d_in[9];
  const float* aW2 = (const float*)d_in[10];
  const float* ab2 = (const float*)d_in[11];
  const float* aW3 = (const float*)d_in[12];
  const float* ab3 = (const float*)d_in[13];
  float* outf = (float*)d_out;

  fused_graph<<<256,256,0,stream>>>(x, rem, outf,
                                    pW1,pb1,pW2,pb2,pW3,pb3,
                                    aW1,ab1,aW2,ab2,aW3,ab3);
}

// Round 2
// 1026.791 us; speedup vs baseline: 1.1852x; 1.1852x over previous
//
#include <hip/hip_runtime.h>

#define NN 4096

// Scratch in the device image -- fully rewritten before every read on every
// call (stateless across calls), no dependence on ws_size.
__device__ float g_outf[NN*8];
__device__ float g_agg0[NN*8];
__device__ float g_agg1[NN*8];

__device__ __forceinline__ float lrelu(float x){ return x > 0.0f ? x : 0.01f * x; }

// Full 3-layer MLP (8->16->8->8), leaky_relu(0.01) after every layer.
__device__ void mlp3(const float* in,
                     const float* W1, const float* b1,
                     const float* W2, const float* b2,
                     const float* W3, const float* b3, float* out)
{
  float h1[16];
  #pragma unroll
  for (int m=0;m<16;m++){
    float s = b1[m];
    #pragma unroll
    for (int k=0;k<8;k++) s += in[k]*W1[k*16+m];
    h1[m] = lrelu(s);
  }
  float h2[8];
  #pragma unroll
  for (int m=0;m<8;m++){
    float s = b2[m];
    #pragma unroll
    for (int k=0;k<16;k++) s += h1[k]*W2[k*8+m];
    h2[m] = lrelu(s);
  }
  #pragma unroll
  for (int c=0;c<8;c++){
    float s = b3[c];
    #pragma unroll
    for (int k=0;k<8;k++) s += h2[k]*W3[k*8+c];
    out[c] = lrelu(s);
  }
}

// out0 = MLP_p(x); agg0 = MLP_a(out0). One thread per row.
__global__ __launch_bounds__(256) void init_kernel(
    const float* __restrict__ x,
    const float* pW1,const float* pb1,const float* pW2,const float* pb2,const float* pW3,const float* pb3,
    const float* aW1,const float* ab1,const float* aW2,const float* ab2,const float* aW3,const float* ab3)
{
  int i = blockIdx.x*256 + threadIdx.x;
  float in[8];
  #pragma unroll
  for (int k=0;k<8;k++) in[k] = x[i*8+k];
  float o[8];
  mlp3(in, pW1,pb1,pW2,pb2,pW3,pb3, o);
  #pragma unroll
  for (int c=0;c<8;c++) g_outf[i*8+c] = o[c];
  float a[8];
  mlp3(o, aW1,ab1,aW2,ab2,aW3,ab3, a);
  #pragma unroll
  for (int c=0;c<8;c++) g_agg0[i*8+c] = a[c];
}

// out[i] += A[i,:] @ aggin  (2 rows per wave, f32), then epilogue computes
// aggout = MLP_a(out_new) lane-parallel, or writes final f32 output at d=7.
// Geometry: 512 blocks x 4 waves x 2 rows = 4096 rows; 2 blocks/CU resident
// (8 waves/CU = 2/SIMD) for latency hiding. A stream (HBM, ~900cy) is
// prefetched 2 iterations ahead; G stream (L2-resident aggin, ~200cy) 1 ahead.
__global__ __launch_bounds__(256,2) void agg_update(
    const float* __restrict__ A, int parity, float* __restrict__ finout,
    const float* __restrict__ aW1,const float* __restrict__ ab1,
    const float* __restrict__ aW2,const float* __restrict__ ab2,
    const float* __restrict__ aW3,const float* __restrict__ ab3)
{
  const float* aggin  = parity ? g_agg1 : g_agg0;
  float*       aggout = parity ? g_agg0 : g_agg1;

  const int lane = threadIdx.x & 63;
  const int wav  = threadIdx.x >> 6;
  const int i0   = (blockIdx.x*4 + wav) * 2;   // 2 rows per wave

  const float4* Ar0 = reinterpret_cast<const float4*>(A + (size_t)(i0+0)*NN) + lane;
  const float4* Ar1 = reinterpret_cast<const float4*>(A + (size_t)(i0+1)*NN) + lane;
  const float4* gp  = reinterpret_cast<const float4*>(aggin) + (size_t)lane*8;

  float acc[2][8];
  #pragma unroll
  for (int r=0;r<2;r++)
    #pragma unroll
    for (int c=0;c<8;c++) acc[r][c] = 0.0f;

  // prologue: 2-deep A prefetch, 1-deep G prefetch
  float4 cA0 = Ar0[0],  cA1 = Ar1[0];
  float4 nA0 = Ar0[64], nA1 = Ar1[64];
  float4 cG[8];
  #pragma unroll
  for (int t=0;t<8;t++) cG[t] = gp[t];

  // lane l covers j = it*256 + 4*l .. +3; wave covers 256 j per iteration
  for (int it=0; it<16; ++it){
    float4 pA0, pA1;
    if (it < 14){
      pA0 = Ar0[(it+2)*64];
      pA1 = Ar1[(it+2)*64];
    }
    float4 fG[8];
    if (it < 15){
      #pragma unroll
      for (int t=0;t<8;t++) fG[t] = gp[(it+1)*512 + t];
    }

    const float av[2][4] = {{cA0.x,cA0.y,cA0.z,cA0.w},
                            {cA1.x,cA1.y,cA1.z,cA1.w}};
    #pragma unroll
    for (int jj=0;jj<4;jj++){
      const float gl[8] = {cG[2*jj].x, cG[2*jj].y, cG[2*jj].z, cG[2*jj].w,
                           cG[2*jj+1].x, cG[2*jj+1].y, cG[2*jj+1].z, cG[2*jj+1].w};
      #pragma unroll
      for (int r=0;r<2;r++){
        const float a = av[r][jj];
        #pragma unroll
        for (int c=0;c<8;c++) acc[r][c] += a*gl[c];
      }
    }

    cA0 = nA0; cA1 = nA1;
    if (it < 14){ nA0 = pA0; nA1 = pA1; }
    if (it < 15){
      #pragma unroll
      for (int t=0;t<8;t++) cG[t] = fG[t];
    }
  }

  // 64-lane butterfly reduce: afterwards every lane holds all 16 totals
  #pragma unroll
  for (int r=0;r<2;r++)
    #pragma unroll
    for (int c=0;c<8;c++){
      float v = acc[r][c];
      #pragma unroll
      for (int s=1;s<64;s<<=1) v += __shfl_xor(v, s, 64);
      acc[r][c] = v;
    }

  const int r = (lane >> 4) & 1, m = lane & 15;
  float* po = g_outf + (size_t)i0*8;

  // new out row for this lane's MLP row (r); compile-time acc indices only
  float rowv[8];
  #pragma unroll
  for (int k=0;k<8;k++) rowv[k] = po[r*8+k] + (r ? acc[1][k] : acc[0][k]);

  // lanes 0..15 write the 16 updated values (loads above precede stores in wave order)
  if (lane < 16){
    float t = 0.0f;
    #pragma unroll
    for (int rr=0;rr<2;rr++)
      #pragma unroll
      for (int cc=0;cc<8;cc++)
        if (rr*8+cc == lane) t = acc[rr][cc];
    float sv = po[lane] + t;
    po[lane] = sv;
    if (finout) finout[(size_t)i0*8 + lane] = sv;
  }

  if (!finout){
    // lane-parallel MLP_a over 2 rows x 16 neurons (lanes 32..63 duplicate
    // lanes 0..31 harmlessly; shfl groups of 16 are row-uniform)
    float h1 = ab1[m];
    #pragma unroll
    for (int k=0;k<8;k++) h1 += rowv[k]*aW1[k*16+m];
    h1 = lrelu(h1);
    const int m8 = m & 7;
    float s2 = ab2[m8];
    #pragma unroll
    for (int k=0;k<16;k++) s2 += __shfl(h1, (lane & 48)+k, 64) * aW2[k*8+m8];
    float h2 = lrelu(s2);
    float s3 = ab3[m8];
    #pragma unroll
    for (int k=0;k<8;k++) s3 += __shfl(h2, (lane & 48)+k, 64) * aW3[k*8+m8];
    float av2 = lrelu(s3);
    if (m < 8 && lane < 32) aggout[(size_t)(i0+r)*8 + m] = av2;
  }
}

extern "C" void kernel_launch(void* const* d_in, const int* in_sizes, int n_in,
                              void* d_out, int out_size, void* d_ws, size_t ws_size,
                              hipStream_t stream)
{
  const float* x   = (const float*)d_in[0];
  const float* rem = (const float*)d_in[1];
  const float* pW1 = (const float*)d_in[2];
  const float* pb1 = (const float*)d_in[3];
  const float* pW2 = (const float*)d_in[4];
  const float* pb2 = (const float*)d_in[5];
  const float* pW3 = (const float*)d_in[6];
  const float* pb3 = (const float*)d_in[7];
  const float* aW1 = (const float*)d_in[8];
  const float* ab1 = (const float*)d_in[9];
  const float* aW2 = (const float*)d_in[10];
  const float* ab2 = (const float*)d_in[11];
  const float* aW3 = (const float*)d_in[12];
  const float* ab3 = (const float*)d_in[13];
  float* outf = (float*)d_out;

  init_kernel<<<16,256,0,stream>>>(x,pW1,pb1,pW2,pb2,pW3,pb3,
                                   aW1,ab1,aW2,ab2,aW3,ab3);
  for (int d=0; d<8; ++d){
    agg_update<<<512,256,0,stream>>>(rem + (size_t)d*NN*NN, (d&1),
                                     (d==7)? outf : (float*)nullptr,
                                     aW1,ab1,aW2,ab2,aW3,ab3);
  }
}

// Round 3
// 772.344 us; speedup vs baseline: 1.5757x; 1.3294x over previous
//
#include <hip/hip_runtime.h>

#define NN 4096

// Scratch in the device image -- fully rewritten before every read on every
// call (stateless across calls), no dependence on ws_size.
// agg buffers are stored TRANSPOSED: aggT[c][j], c=0..7, j=0..4095.
// This makes the per-iteration G loads in agg_update perfectly coalesced
// (lane l reads float4 at column j=4l: contiguous across the wave) instead
// of 128-B-strided gathers that touch 4x more cache lines per instruction.
__device__ float g_outf[NN*8];
__device__ float g_agg0[NN*8];
__device__ float g_agg1[NN*8];

__device__ __forceinline__ float lrelu(float x){ return x > 0.0f ? x : 0.01f * x; }

// Full 3-layer MLP (8->16->8->8), leaky_relu(0.01) after every layer.
__device__ void mlp3(const float* in,
                     const float* W1, const float* b1,
                     const float* W2, const float* b2,
                     const float* W3, const float* b3, float* out)
{
  float h1[16];
  #pragma unroll
  for (int m=0;m<16;m++){
    float s = b1[m];
    #pragma unroll
    for (int k=0;k<8;k++) s += in[k]*W1[k*16+m];
    h1[m] = lrelu(s);
  }
  float h2[8];
  #pragma unroll
  for (int m=0;m<8;m++){
    float s = b2[m];
    #pragma unroll
    for (int k=0;k<16;k++) s += h1[k]*W2[k*8+m];
    h2[m] = lrelu(s);
  }
  #pragma unroll
  for (int c=0;c<8;c++){
    float s = b3[c];
    #pragma unroll
    for (int k=0;k<8;k++) s += h2[k]*W3[k*8+c];
    out[c] = lrelu(s);
  }
}

// out0 = MLP_p(x); agg0T = MLP_a(out0) transposed. One thread per row.
__global__ __launch_bounds__(256) void init_kernel(
    const float* __restrict__ x,
    const float* pW1,const float* pb1,const float* pW2,const float* pb2,const float* pW3,const float* pb3,
    const float* aW1,const float* ab1,const float* aW2,const float* ab2,const float* aW3,const float* ab3)
{
  int i = blockIdx.x*256 + threadIdx.x;
  float in[8];
  #pragma unroll
  for (int k=0;k<8;k++) in[k] = x[i*8+k];
  float o[8];
  mlp3(in, pW1,pb1,pW2,pb2,pW3,pb3, o);
  #pragma unroll
  for (int c=0;c<8;c++) g_outf[i*8+c] = o[c];
  float a[8];
  mlp3(o, aW1,ab1,aW2,ab2,aW3,ab3, a);
  // transposed store: per c, lanes write consecutive i -> coalesced
  #pragma unroll
  for (int c=0;c<8;c++) g_agg0[c*NN + i] = a[c];
}

// out[i] += A[i,:] @ aggin  (4 rows per wave, f32), then epilogue computes
// aggoutT = MLP_a(out_new) lane-parallel, or writes final f32 output at d=7.
// Geometry identical to the proven round-0 kernel: 256 blocks x 4 waves x
// 4 rows, 1 block/CU. Only the agg layout changed (transposed).
__global__ __launch_bounds__(256,1) void agg_update(
    const float* __restrict__ A, int parity, float* __restrict__ finout,
    const float* __restrict__ aW1,const float* __restrict__ ab1,
    const float* __restrict__ aW2,const float* __restrict__ ab2,
    const float* __restrict__ aW3,const float* __restrict__ ab3)
{
  const float* aggin  = parity ? g_agg1 : g_agg0;
  float*       aggout = parity ? g_agg0 : g_agg1;

  const int lane = threadIdx.x & 63;
  const int wav  = threadIdx.x >> 6;
  const int i0   = (blockIdx.x*4 + wav) * 4;   // 4 rows per wave

  const float4* Ar0 = reinterpret_cast<const float4*>(A + (size_t)(i0+0)*NN) + lane;
  const float4* Ar1 = reinterpret_cast<const float4*>(A + (size_t)(i0+1)*NN) + lane;
  const float4* Ar2 = reinterpret_cast<const float4*>(A + (size_t)(i0+2)*NN) + lane;
  const float4* Ar3 = reinterpret_cast<const float4*>(A + (size_t)(i0+3)*NN) + lane;
  // transposed agg: row c at float4 index c*(NN/4); lane offset 4*lane floats
  const float4* gpT = reinterpret_cast<const float4*>(aggin) + lane;

  float acc[4][8];
  #pragma unroll
  for (int r=0;r<4;r++)
    #pragma unroll
    for (int c=0;c<8;c++) acc[r][c] = 0.0f;

  // lane l covers j = it*256 + 4*l .. +3; wave covers 256 j per iteration
  for (int it=0; it<16; ++it){
    float4 a0 = Ar0[it*64];
    float4 a1 = Ar1[it*64];
    float4 a2 = Ar2[it*64];
    float4 a3 = Ar3[it*64];
    // G[c] = aggT[c][j0..j0+3], contiguous across lanes per instruction
    float4 G[8];
    #pragma unroll
    for (int c=0;c<8;c++) G[c] = gpT[c*(NN/4) + it*64];

    const float av[4][4] = {{a0.x,a0.y,a0.z,a0.w},
                            {a1.x,a1.y,a1.z,a1.w},
                            {a2.x,a2.y,a2.z,a2.w},
                            {a3.x,a3.y,a3.z,a3.w}};
    #pragma unroll
    for (int jj=0;jj<4;jj++){
      const float gl[8] = {
        jj==0 ? G[0].x : jj==1 ? G[0].y : jj==2 ? G[0].z : G[0].w,
        jj==0 ? G[1].x : jj==1 ? G[1].y : jj==2 ? G[1].z : G[1].w,
        jj==0 ? G[2].x : jj==1 ? G[2].y : jj==2 ? G[2].z : G[2].w,
        jj==0 ? G[3].x : jj==1 ? G[3].y : jj==2 ? G[3].z : G[3].w,
        jj==0 ? G[4].x : jj==1 ? G[4].y : jj==2 ? G[4].z : G[4].w,
        jj==0 ? G[5].x : jj==1 ? G[5].y : jj==2 ? G[5].z : G[5].w,
        jj==0 ? G[6].x : jj==1 ? G[6].y : jj==2 ? G[6].z : G[6].w,
        jj==0 ? G[7].x : jj==1 ? G[7].y : jj==2 ? G[7].z : G[7].w};
      #pragma unroll
      for (int r=0;r<4;r++){
        const float a = av[r][jj];
        #pragma unroll
        for (int c=0;c<8;c++) acc[r][c] += a*gl[c];
      }
    }
  }

  // 64-lane butterfly reduce: afterwards every lane holds all 32 totals
  #pragma unroll
  for (int r=0;r<4;r++)
    #pragma unroll
    for (int c=0;c<8;c++){
      float v = acc[r][c];
      #pragma unroll
      for (int s=1;s<64;s<<=1) v += __shfl_xor(v, s, 64);
      acc[r][c] = v;
    }

  const int r = lane >> 4, m = lane & 15;
  float* po = g_outf + (size_t)i0*8;

  // new out row for this lane's MLP row (r = lane>>4)
  float rowv[8];
  #pragma unroll
  for (int k=0;k<8;k++) rowv[k] = po[r*8+k] + acc[r][k];

  // lanes 0..31 write the 32 updated values (loads above precede stores in wave order)
  if (lane < 32){
    float t = 0.0f;
    #pragma unroll
    for (int rr=0;rr<4;rr++)
      #pragma unroll
      for (int cc=0;cc<8;cc++)
        if (rr*8+cc == lane) t = acc[rr][cc];
    float sv = po[lane] + t;
    po[lane] = sv;
    if (finout) finout[(size_t)i0*8 + lane] = sv;
  }

  if (!finout){
    // lane-parallel MLP_a over 4 rows x 16 neurons
    float h1 = ab1[m];
    #pragma unroll
    for (int k=0;k<8;k++) h1 += rowv[k]*aW1[k*16+m];
    h1 = lrelu(h1);
    const int m8 = m & 7;
    float s2 = ab2[m8];
    #pragma unroll
    for (int k=0;k<16;k++) s2 += __shfl(h1, (lane & 48)+k, 64) * aW2[k*8+m8];
    float h2 = lrelu(s2);
    float s3 = ab3[m8];
    #pragma unroll
    for (int k=0;k<8;k++) s3 += __shfl(h2, (lane & 48)+k, 64) * aW3[k*8+m8];
    float av2 = lrelu(s3);
    // transposed store: aggT[m][i0+r]
    if (m < 8) aggout[(size_t)m*NN + (i0+r)] = av2;
  }
}

extern "C" void kernel_launch(void* const* d_in, const int* in_sizes, int n_in,
                              void* d_out, int out_size, void* d_ws, size_t ws_size,
                              hipStream_t stream)
{
  const float* x   = (const float*)d_in[0];
  const float* rem = (const float*)d_in[1];
  const float* pW1 = (const float*)d_in[2];
  const float* pb1 = (const float*)d_in[3];
  const float* pW2 = (const float*)d_in[4];
  const float* pb2 = (const float*)d_in[5];
  const float* pW3 = (const float*)d_in[6];
  const float* pb3 = (const float*)d_in[7];
  const float* aW1 = (const float*)d_in[8];
  const float* ab1 = (const float*)d_in[9];
  const float* aW2 = (const float*)d_in[10];
  const float* ab2 = (const float*)d_in[11];
  const float* aW3 = (const float*)d_in[12];
  const float* ab3 = (const float*)d_in[13];
  float* outf = (float*)d_out;

  init_kernel<<<16,256,0,stream>>>(x,pW1,pb1,pW2,pb2,pW3,pb3,
                                   aW1,ab1,aW2,ab2,aW3,ab3);
  for (int d=0; d<8; ++d){
    agg_update<<<256,256,0,stream>>>(rem + (size_t)d*NN*NN, (d&1),
                                     (d==7)? outf : (float*)nullptr,
                                     aW1,ab1,aW2,ab2,aW3,ab3);
  }
}